// Round 15
// baseline (494.084 us; speedup 1.0000x reference)
//
#include <hip/hip_runtime.h>
#include <hip/hip_bf16.h>

#define NNODES 50000
#define NEDGES 600000
#define NGRAPHS 128
#define EMB 128
#define NLAYERS 5
#define BN_EPS 1e-5f
#define STATW 8                               // stat fanout ways
#define SCAN_BLOCKS ((NNODES + 255) / 256)    // 196
#define NSB2 ((NNODES + 31) / 32)             // 1563 node_S blocks (8 lanes/node)
#define EAMB ((NNODES + 127) / 128)           // 391 enc_atom MFMA blocks
#define BPB2 ((NLAYERS * 32768 + 255) / 256)  // 640 bprep blocks (Wl/Wr only)

typedef short s16x8 __attribute__((ext_vector_type(8)));
typedef float f32x16 __attribute__((ext_vector_type(16)));

__device__ __forceinline__ short f2bf(float f) {
    unsigned u = __builtin_bit_cast(unsigned, f);
    unsigned r = (u + 0x7fffu + ((u >> 16) & 1u)) >> 16;  // RNE
    return (short)r;
}
__device__ __forceinline__ float bf2f(short s) {
    return __builtin_bit_cast(float, ((unsigned)(unsigned short)s) << 16);
}

// sum the STATW fanout copies for column t (t<128): returns {sum, sumsq}
__device__ __forceinline__ float2 stat_sum(const float* __restrict__ st, int t) {
    float s = 0.f, q = 0.f;
#pragma unroll
    for (int k = 0; k < STATW; k++) {
        s += st[k * 256 + t];
        q += st[k * 256 + 128 + t];
    }
    return make_float2(s, q);
}

// LDS inclusive scan of the 196 part[] entries (all 256 threads participate).
// After this, rowptr(n) = local_excl[n] + (n>=256 ? sps[(n>>8)-1] : 0),
// and rowptr(NNODES) = sps[SCAN_BLOCKS-1].
__device__ __forceinline__ void part_scan(const int* __restrict__ part,
                                          int* __restrict__ sps, int t) {
    int v = (t < SCAN_BLOCKS) ? part[t] : 0;
    sps[t] = v;
    __syncthreads();
    for (int off = 1; off < 256; off <<= 1) {
        int u = (t >= off) ? sps[t - off] : 0;
        __syncthreads();
        sps[t] += u;
        __syncthreads();
    }
}
__device__ __forceinline__ int rp_of(const int* __restrict__ local_excl,
                                     const int* __restrict__ sps, int n) {
    if (n >= NNODES) return sps[SCAN_BLOCKS - 1];
    int blk = n >> 8;
    return local_excl[n] + (blk ? sps[blk - 1] : 0);
}

// ---------------- init: zero deg/stat + build Wa MFMA fragments --------------
// Waf built HERE (dispatch 1) so prep2's enc_atom consumes it across a
// dispatch boundary — no intra-dispatch producer/consumer race (R13 lesson).
__global__ __launch_bounds__(256) void init_kernel(int* __restrict__ deg,
                                                   float* __restrict__ stat,
                                                   const float* __restrict__ Wa,
                                                   short* __restrict__ Waf) {
    int i = blockIdx.x * 256 + threadIdx.x;
    if (i < NNODES) deg[i] = 0;
    if (i < NLAYERS * STATW * 256) stat[i] = 0.f;
    if (i < 48 * 128) {
        int k = i >> 7, col = i & 127;
        float w = Wa[k * 128 + col];
        short hi = f2bf(w);
        short lo = f2bf(w - bf2f(hi));
        int ks = k >> 4, half = (k >> 3) & 1, j = k & 7;
        int nt = col >> 5, n32 = col & 31;
        int fo = ((nt * 2 + half) * 32 + n32) * 8 + j;
        Waf[ks * 4096 + fo] = hi;
        Waf[ks * 4096 + 2048 + fo] = lo;
    }
}

// ---------------- deg histogram + per-edge rank (atomic return value) --------
__global__ __launch_bounds__(256) void deg_kernel(const int* __restrict__ ei,
                                                  int* __restrict__ deg,
                                                  int* __restrict__ rank) {
    int e = blockIdx.x * 256 + threadIdx.x;
    if (e >= NEDGES) return;
    rank[e] = atomicAdd(&deg[ei[NEDGES + e]], 1);
}

// ---------------- scan1: per-256-chunk exclusive scan + chunk totals ---------
__global__ __launch_bounds__(256) void scan1(const int* __restrict__ deg,
                                             int* __restrict__ local_excl,
                                             int* __restrict__ part) {
    __shared__ int sh[256];
    int t = threadIdx.x;
    int i = blockIdx.x * 256 + t;
    int v = (i < NNODES) ? deg[i] : 0;
    sh[t] = v;
    __syncthreads();
    for (int off = 1; off < 256; off <<= 1) {
        int u = (t >= off) ? sh[t - off] : 0;
        __syncthreads();
        sh[t] += u;
        __syncthreads();
    }
    if (i < NNODES) local_excl[i] = sh[t] - v;
    if (t == 255) part[blockIdx.x] = sh[255];
}

// ---------------- fill CSR: pos = rowptr(dst) + rank[e], NO atomic -----------
// rowptr reconstructed in-block from part scan (scan23 dispatch eliminated).
__global__ __launch_bounds__(256) void edge_fill(const int* __restrict__ ei,
                                                 const float* __restrict__ ew,
                                                 const float* __restrict__ eattr,
                                                 const int* __restrict__ local_excl,
                                                 const int* __restrict__ part,
                                                 const int* __restrict__ rank,
                                                 int* __restrict__ epk) {
    __shared__ int sps[256];
    int t = threadIdx.x;
    part_scan(part, sps, t);   // ALL threads, before any return
    int e = blockIdx.x * 256 + t;
    if (e >= NEDGES) return;
    int src = ei[e];
    int dst = ei[NEDGES + e];
    int pos = rp_of(local_excl, sps, dst) + rank[e];
    int pk[8];
    pk[0] = src;
    pk[1] = __float_as_int(ew[e]);
    unsigned short a[12];
#pragma unroll
    for (int j = 0; j < 11; j++) a[j] = (unsigned short)f2bf(eattr[e * 11 + j]);
    a[11] = 0;
#pragma unroll
    for (int j = 0; j < 6; j++)
        pk[2 + j] = (int)a[2 * j] | ((int)a[2 * j + 1] << 16);
    int* dstp = epk + (size_t)pos * 8;
    *(int4*)dstp = *(int4*)pk;
    *(int4*)(dstp + 4) = *(int4*)(pk + 4);
}

// ---------------- prep2: {node_S (8 lanes/node) | enc_atom MFMA | bprep} -----
__global__ __launch_bounds__(256) void prep2(const int* __restrict__ local_excl,
                                             const int* __restrict__ part,
                                             const int* __restrict__ epk,
                                             int2* __restrict__ epg,
                                             const float* __restrict__ Wb,
                                             const float* __restrict__ bbond,
                                             short* __restrict__ Ehi,
                                             const float* __restrict__ X,
                                             const float* __restrict__ ba,
                                             short* __restrict__ Hhi,
                                             const float* __restrict__ Wl,
                                             const float* __restrict__ Wr,
                                             short* __restrict__ Bf,
                                             const short* __restrict__ Waf) {
    __shared__ float shpool[1536];  // node_S: Wb_s 1408 + bb_s 128
    __shared__ int sps[256];
    int blk = blockIdx.x;
    int t = threadIdx.x;

    if (blk < NSB2) {
        // ---- node_S: 8 lanes per node stride the edge list; shfl-reduce ----
        float* Wb_s = shpool;        // 11*128
        float* bb_s = shpool + 1408; // 128
        for (int i = t; i < 1408; i += 256) Wb_s[i] = Wb[i];
        if (t < 128) bb_s[t] = bbond[t];
        part_scan(part, sps, t);     // includes barriers covering Wb_s too
        int sub = t & 7, slot = t >> 3;
        int node = blk * 32 + slot;
        float s[11];
#pragma unroll
        for (int j = 0; j < 11; j++) s[j] = 0.f;
        float ws = 0.f;
        if (node < NNODES) {
            int b = rp_of(local_excl, sps, node);
            int e = rp_of(local_excl, sps, node + 1);
            for (int p = b + sub; p < e; p += 8) {
                const int* pk = epk + (size_t)p * 8;
                int4 lo = *(const int4*)pk;
                int4 hi = *(const int4*)(pk + 4);
                float w = __int_as_float(lo.y);
                ws += w;
                epg[p] = make_int2(lo.x, lo.y);   // compact {src,w} record
                int packed[6] = {lo.z, lo.w, hi.x, hi.y, hi.z, hi.w};
#pragma unroll
                for (int j = 0; j < 11; j++) {
                    short v = (short)((packed[j >> 1] >> ((j & 1) * 16)) & 0xffff);
                    s[j] += bf2f(v) * w;
                }
            }
        }
        // butterfly reduce across the node's 8 lanes
#pragma unroll
        for (int m = 1; m < 8; m <<= 1) {
#pragma unroll
            for (int j = 0; j < 11; j++) s[j] += __shfl_xor(s[j], m);
            ws += __shfl_xor(ws, m);
        }
        if (node < NNODES) {
            int c0 = sub * 16;
            short* erow = Ehi + (size_t)node * 128 + c0;
#pragma unroll
            for (int cc = 0; cc < 2; cc++) {
                s16x8 o;
#pragma unroll
                for (int jj = 0; jj < 8; jj++) {
                    int c = c0 + cc * 8 + jj;
                    float a = bb_s[c] * ws;
#pragma unroll
                    for (int j = 0; j < 11; j++) a += s[j] * Wb_s[j * 128 + c];
                    o[jj] = f2bf(a);
                }
                *(s16x8*)(erow + cc * 8) = o;
            }
        }
    } else if (blk < NSB2 + EAMB) {
        // ---- enc_atom via MFMA: h0 = X @ Wa + ba, K=48 = 3 k-steps ----
        int wave = t >> 6, lane = t & 63;
        int n32 = lane & 31, half = lane >> 5;
        int row0 = (blk - NSB2) * 128 + wave * 32;
        int myrow = row0 + n32;
        bool rowok = myrow < NNODES;
        f32x16 acc[4];
#pragma unroll
        for (int i = 0; i < 4; i++) acc[i] = (f32x16)(0.f);
        const short* wb0 = Waf + half * 256 + n32 * 8;
#pragma unroll
        for (int ks = 0; ks < 3; ks++) {
            s16x8 ah = {0, 0, 0, 0, 0, 0, 0, 0};
            if (rowok) {
                const float* xp = X + (size_t)myrow * 48 + ks * 16 + half * 8;
                float4 x0 = *(const float4*)xp;
                float4 x1 = *(const float4*)(xp + 4);
                ah[0] = f2bf(x0.x); ah[1] = f2bf(x0.y);
                ah[2] = f2bf(x0.z); ah[3] = f2bf(x0.w);
                ah[4] = f2bf(x1.x); ah[5] = f2bf(x1.y);
                ah[6] = f2bf(x1.z); ah[7] = f2bf(x1.w);
            }
            const short* wbn = wb0 + ks * 4096;
#pragma unroll
            for (int nt = 0; nt < 4; nt++) {
                s16x8 bh = *(const s16x8*)(wbn + nt * 512);
                s16x8 bl = *(const s16x8*)(wbn + 2048 + nt * 512);
                acc[nt] = __builtin_amdgcn_mfma_f32_32x32x16_bf16(ah, bh, acc[nt], 0, 0, 0);
                acc[nt] = __builtin_amdgcn_mfma_f32_32x32x16_bf16(ah, bl, acc[nt], 0, 0, 0);
            }
        }
#pragma unroll
        for (int nt = 0; nt < 4; nt++) {
            int col = nt * 32 + n32;
            float bb = ba[col];
#pragma unroll
            for (int reg = 0; reg < 16; reg++) {
                int r = row0 + (reg & 3) + 8 * (reg >> 2) + 4 * half;
                if (r < NNODES) Hhi[(size_t)r * 128 + col] = f2bf(acc[nt][reg] + bb);
            }
        }
    } else {
        // ---- bprep: Wl/Wr fragments, hi/lo planes ----
        int idx = (blk - NSB2 - EAMB) * 256 + t;
        if (idx >= NLAYERS * 32768) return;
        int layer = idx >> 15;
        int r = idx & 32767;
        int k = r >> 7, col = r & 127;
        float w = (k < 128) ? Wl[layer * 16384 + k * 128 + col]
                            : Wr[layer * 16384 + (k - 128) * 128 + col];
        short hi = f2bf(w);
        short lo = f2bf(w - bf2f(hi));
        int ks = k >> 4, half = (k >> 3) & 1, j = k & 7;
        int nt = col >> 5, n32 = col & 31;
        int fo = ((nt * 2 + half) * 32 + n32) * 8 + j;
        short* base = Bf + (size_t)layer * 65536 + ks * 4096;
        base[fo] = hi;
        base[2048 + fo] = lo;
    }
}

// ---------------- aggregation with inline BN+ReLU of the source -------------
__global__ __launch_bounds__(256) void agg_kernel(const short* __restrict__ Hsrc,
                                                  const short* __restrict__ Ehi,
                                                  const int* __restrict__ local_excl,
                                                  const int* __restrict__ part,
                                                  const int2* __restrict__ epg,
                                                  const float* __restrict__ stat,
                                                  const float* __restrict__ gamma,
                                                  const float* __restrict__ beta,
                                                  short* __restrict__ Ahi) {
    __shared__ float cscs[128], cshs[128];
    __shared__ int sps[256];
    int t = threadIdx.x;
    if (t < 128) {
        float sc = 1.f, sh = 0.f;
        if (stat) {
            const float invM = 1.f / (float)NNODES;
            float2 sq = stat_sum(stat, t);
            float mu = sq.x * invM;
            float var = sq.y * invM - mu * mu;
            sc = gamma[t] * rsqrtf(var + BN_EPS);
            sh = beta[t] - mu * sc;
        }
        cscs[t] = sc;
        cshs[t] = sh;
    }
    part_scan(part, sps, t);   // barriers also publish cscs/cshs
    int lane = t & 15, grp = t >> 4;
    int c8 = lane * 8;
    int node = blockIdx.x * 16 + grp;
    if (node >= NNODES) return;
    float rlo = stat ? 0.f : -3.4e38f;
    float sc[8], sh[8];
#pragma unroll
    for (int j = 0; j < 8; j++) { sc[j] = cscs[c8 + j]; sh[j] = cshs[c8 + j]; }
    int b = rp_of(local_excl, sps, node);
    int e = rp_of(local_excl, sps, node + 1);
    float s[8];
#pragma unroll
    for (int j = 0; j < 8; j++) s[j] = 0.f;
    int p = b;
    for (; p + 3 < e; p += 4) {
        int2 e0 = epg[p], e1 = epg[p + 1], e2 = epg[p + 2], e3 = epg[p + 3];
        float w0 = __int_as_float(e0.y), w1 = __int_as_float(e1.y);
        float w2 = __int_as_float(e2.y), w3 = __int_as_float(e3.y);
        s16x8 h0 = *(const s16x8*)&Hsrc[(size_t)e0.x * 128 + c8];
        s16x8 h1 = *(const s16x8*)&Hsrc[(size_t)e1.x * 128 + c8];
        s16x8 h2 = *(const s16x8*)&Hsrc[(size_t)e2.x * 128 + c8];
        s16x8 h3 = *(const s16x8*)&Hsrc[(size_t)e3.x * 128 + c8];
#pragma unroll
        for (int j = 0; j < 8; j++) {
            float v0 = fmaxf(bf2f(h0[j]) * sc[j] + sh[j], rlo);
            float v1 = fmaxf(bf2f(h1[j]) * sc[j] + sh[j], rlo);
            float v2 = fmaxf(bf2f(h2[j]) * sc[j] + sh[j], rlo);
            float v3 = fmaxf(bf2f(h3[j]) * sc[j] + sh[j], rlo);
            s[j] += v0 * w0 + v1 * w1 + v2 * w2 + v3 * w3;
        }
    }
    for (; p < e; p++) {
        int2 pk0 = epg[p];
        float w0 = __int_as_float(pk0.y);
        s16x8 h0 = *(const s16x8*)&Hsrc[(size_t)pk0.x * 128 + c8];
#pragma unroll
        for (int j = 0; j < 8; j++)
            s[j] += fmaxf(bf2f(h0[j]) * sc[j] + sh[j], rlo) * w0;
    }
    float inv = 1.f / fmaxf((float)(e - b), 1.f);
    s16x8 ea = *(const s16x8*)&Ehi[(size_t)node * 128 + c8];
    s16x8 o;
#pragma unroll
    for (int j = 0; j < 8; j++) o[j] = f2bf((s[j] + bf2f(ea[j])) * inv);
    *(s16x8*)&Ahi[(size_t)node * 128 + c8] = o;
}

// ---------------- MFMA GEMM (128-row blocks, 4 waves x 128 cols) -------------
// BN inline on h@Wr half; stat atomics fanned 8 ways (slot = blockIdx&7).
__global__ __launch_bounds__(256) void layer_gemm(const short* __restrict__ Ahi,
                                                  const short* __restrict__ Hsrc,
                                                  const float* __restrict__ statp,
                                                  const float* __restrict__ gamma,
                                                  const float* __restrict__ beta,
                                                  const short* __restrict__ Bf,
                                                  const float* __restrict__ bias,
                                                  short* __restrict__ Cbf,
                                                  float* __restrict__ stat) {
    __shared__ float s_s[128], s_q[128];
    __shared__ float csc[128], csh[128];
    int t = threadIdx.x;
    int wave = t >> 6, lane = t & 63;
    int n32 = lane & 31, half = lane >> 5;
    int row0 = blockIdx.x * 128 + wave * 32;

    if (t < 128) {
        s_s[t] = 0.f;
        s_q[t] = 0.f;
        float sc = 1.f, sh = 0.f;
        if (statp) {
            const float invM = 1.f / (float)NNODES;
            float2 sq = stat_sum(statp, t);
            float mu = sq.x * invM;
            float var = sq.y * invM - mu * mu;
            sc = gamma[t] * rsqrtf(var + BN_EPS);
            sh = beta[t] - mu * sc;
        }
        csc[t] = sc;
        csh[t] = sh;
    }
    __syncthreads();
    float rlo = statp ? 0.f : -3.4e38f;

    int myrow = row0 + n32;
    bool rowok = myrow < NNODES;
    size_t rbase = (size_t)myrow * 128;
    int acol = half * 8;

    f32x16 acc[4];
#pragma unroll
    for (int i = 0; i < 4; i++) acc[i] = (f32x16)(0.f);

    const short* bb0 = Bf + half * 256 + n32 * 8;

    s16x8 ahA = {0, 0, 0, 0, 0, 0, 0, 0}, ahB = {0, 0, 0, 0, 0, 0, 0, 0};
    s16x8 bhA[4], blA[4], bhB[4], blB[4];
    if (rowok) {
        ahA = *(const s16x8*)(Ahi + rbase + acol);
        ahB = *(const s16x8*)(Ahi + rbase + 16 + acol);
    }
#pragma unroll
    for (int nt = 0; nt < 4; nt++) {
        bhA[nt] = *(const s16x8*)(bb0 + nt * 512);
        blA[nt] = *(const s16x8*)(bb0 + 2048 + nt * 512);
        bhB[nt] = *(const s16x8*)(bb0 + 4096 + nt * 512);
        blB[nt] = *(const s16x8*)(bb0 + 4096 + 2048 + nt * 512);
    }

#pragma unroll
    for (int ks = 0; ks < 16; ks++) {
        s16x8 ahC = {0, 0, 0, 0, 0, 0, 0, 0};
        s16x8 bhC[4], blC[4];
        if (ks < 14) {
            int kn = ks + 2;
            if (rowok) {
                if (kn < 8) {
                    ahC = *(const s16x8*)(Ahi + rbase + kn * 16 + acol);
                } else {
                    s16x8 hv = *(const s16x8*)(Hsrc + rbase + (kn & 7) * 16 + acol);
                    int kc = (kn & 7) * 16 + acol;
#pragma unroll
                    for (int j = 0; j < 8; j++)
                        ahC[j] = f2bf(fmaxf(bf2f(hv[j]) * csc[kc + j] +
                                            csh[kc + j], rlo));
                }
            }
            const short* bbn = bb0 + kn * 4096;
#pragma unroll
            for (int nt = 0; nt < 4; nt++) {
                bhC[nt] = *(const s16x8*)(bbn + nt * 512);
                blC[nt] = *(const s16x8*)(bbn + 2048 + nt * 512);
            }
        }
#pragma unroll
        for (int nt = 0; nt < 4; nt++) {
            acc[nt] = __builtin_amdgcn_mfma_f32_32x32x16_bf16(ahA, bhA[nt], acc[nt], 0, 0, 0);
            acc[nt] = __builtin_amdgcn_mfma_f32_32x32x16_bf16(ahA, blA[nt], acc[nt], 0, 0, 0);
        }
        ahA = ahB;
        ahB = ahC;
#pragma unroll
        for (int nt = 0; nt < 4; nt++) {
            bhA[nt] = bhB[nt];
            blA[nt] = blB[nt];
            bhB[nt] = bhC[nt];
            blB[nt] = blC[nt];
        }
    }

    // epilogue: bias, bf16 C write, fused BN partial stats
#pragma unroll
    for (int nt = 0; nt < 4; nt++) {
        int col = nt * 32 + n32;
        float bb = bias[col];
        float ss = 0.f, qq = 0.f;
#pragma unroll
        for (int reg = 0; reg < 16; reg++) {
            int r = row0 + (reg & 3) + 8 * (reg >> 2) + 4 * half;
            if (r < NNODES) {
                float v = acc[nt][reg] + bb;
                Cbf[(size_t)r * 128 + col] = f2bf(v);
                ss += v;
                qq += v * v;
            }
        }
        ss += __shfl_xor(ss, 32);
        qq += __shfl_xor(qq, 32);
        if (half == 0) {
            atomicAdd(&s_s[col], ss);
            atomicAdd(&s_q[col], qq);
        }
    }
    __syncthreads();
    if (t < 128) {
        int slot = blockIdx.x & (STATW - 1);
        atomicAdd(&stat[slot * 256 + t], s_s[t]);
        atomicAdd(&stat[slot * 256 + 128 + t], s_q[t]);
    }
}

// ---------------- pool5: one block per (graph, layer), NO atomics ------------
__global__ __launch_bounds__(256) void pool5(const short* __restrict__ Cbf,
                                             const float* __restrict__ stat,
                                             const float* __restrict__ gamma,
                                             const float* __restrict__ beta,
                                             const int* __restrict__ batch,
                                             float* __restrict__ pool,
                                             float* __restrict__ Hf32) {
    __shared__ float csc[128], csh[128];
    __shared__ float sred[8][128];
    __shared__ int srange[2];
    int t = threadIdx.x;
    int u = blockIdx.x;
    int g = u / NLAYERS, l = u - g * NLAYERS;
    if (t < 2) {
        int target = g + t;
        int lo = 0, hi = NNODES;
        while (lo < hi) {
            int mid = (lo + hi) >> 1;
            if (batch[mid] < target) lo = mid + 1; else hi = mid;
        }
        srange[t] = lo;
    }
    if (t < 128) {
        const float invM = 1.f / (float)NNODES;
        float2 sq = stat_sum(stat + l * STATW * 256, t);
        float mu = sq.x * invM;
        float var = sq.y * invM - mu * mu;
        float sc = gamma[l * 128 + t] * rsqrtf(var + BN_EPS);
        csc[t] = sc;
        csh[t] = beta[l * 128 + t] - mu * sc;
    }
    __syncthreads();
    int gstart = srange[0], gend = srange[1];
    int lane = t & 31, grp = t >> 5;
    int c4 = lane * 4;
    float4 sc = *(const float4*)&csc[c4];
    float4 sh = *(const float4*)&csh[c4];
    const short* Cl = Cbf + (size_t)l * NNODES * 128;
    float4 accp = make_float4(0.f, 0.f, 0.f, 0.f);
    int relu = (l < NLAYERS - 1);
    for (int r = gstart + grp; r < gend; r += 8) {
        ushort4 cv = *(const ushort4*)&Cl[(size_t)r * 128 + c4];
        float4 v;
        v.x = bf2f((short)cv.x) * sc.x + sh.x;
        v.y = bf2f((short)cv.y) * sc.y + sh.y;
        v.z = bf2f((short)cv.z) * sc.z + sh.z;
        v.w = bf2f((short)cv.w) * sc.w + sh.w;
        if (relu) {
            v.x = fmaxf(v.x, 0.f);
            v.y = fmaxf(v.y, 0.f);
            v.z = fmaxf(v.z, 0.f);
            v.w = fmaxf(v.w, 0.f);
        } else {
            *(float4*)&Hf32[(size_t)r * 128 + c4] = v;
        }
        accp.x += v.x;
        accp.y += v.y;
        accp.z += v.z;
        accp.w += v.w;
    }
    sred[grp][c4 + 0] = accp.x;
    sred[grp][c4 + 1] = accp.y;
    sred[grp][c4 + 2] = accp.z;
    sred[grp][c4 + 3] = accp.w;
    __syncthreads();
    if (t < 128) {
        float s = 0.f;
#pragma unroll
        for (int k = 0; k < 8; k++) s += sred[k][t];
        pool[(size_t)g * 640 + l * 128 + t] = s;
    }
}

extern "C" void kernel_launch(void* const* d_in, const int* in_sizes, int n_in,
                              void* d_out, int out_size, void* d_ws, size_t ws_size,
                              hipStream_t stream) {
    const int* batch = (const int*)d_in[0];
    const float* x = (const float*)d_in[1];
    const int* edge_index = (const int*)d_in[2];
    const float* edge_attr = (const float*)d_in[3];
    const float* edge_weight = (const float*)d_in[4];
    const float* W_atom = (const float*)d_in[5];
    const float* b_atom = (const float*)d_in[6];
    const float* W_bond = (const float*)d_in[7];
    const float* b_bond = (const float*)d_in[8];
    const float* Wl = (const float*)d_in[9];
    const float* bl = (const float*)d_in[10];
    const float* Wr = (const float*)d_in[11];
    const float* gamma = (const float*)d_in[12];
    const float* beta = (const float*)d_in[13];
    float* out = (float*)d_out;

    // ---- workspace layout ----
    char* ws = (char*)d_ws;
    size_t off = 0;
    auto alloc = [&](size_t bytes) -> void* {
        void* p = ws + off;
        off += (bytes + 255) & ~(size_t)255;
        return p;
    };
    short* Hhi = (short*)alloc((size_t)NNODES * 128 * 2);
    short* Ahi = (short*)alloc((size_t)NNODES * 128 * 2);
    short* Ehi = (short*)alloc((size_t)NNODES * 128 * 2);
    short* Cbf = (short*)alloc((size_t)NLAYERS * NNODES * 128 * 2);  // 5 layers
    int* epk = (int*)alloc((size_t)NEDGES * 32);
    int2* epg = (int2*)alloc((size_t)NEDGES * 8);
    int* rank = (int*)alloc((size_t)NEDGES * 4);
    int* deg = (int*)alloc((size_t)NNODES * 4);
    float* stat = (float*)alloc(NLAYERS * STATW * 256 * 4);
    int* local_excl = (int*)alloc((size_t)NNODES * 4);
    int* part = (int*)alloc(SCAN_BLOCKS * 4);
    short* Bf = (short*)alloc((size_t)NLAYERS * 65536 * 2);
    short* Waf = (short*)alloc((size_t)3 * 4096 * 2);

    // ---- preprocessing (5 dispatches) ----
    init_kernel<<<SCAN_BLOCKS, 256, 0, stream>>>(deg, stat, W_atom, Waf);
    deg_kernel<<<(NEDGES + 255) / 256, 256, 0, stream>>>(edge_index, deg, rank);
    scan1<<<SCAN_BLOCKS, 256, 0, stream>>>(deg, local_excl, part);
    edge_fill<<<(NEDGES + 255) / 256, 256, 0, stream>>>(edge_index, edge_weight,
                                                        edge_attr, local_excl, part,
                                                        rank, epk);
    prep2<<<NSB2 + EAMB + BPB2, 256, 0, stream>>>(local_excl, part, epk, epg,
                                                  W_bond, b_bond, Ehi, x, b_atom,
                                                  Hhi, Wl, Wr, Bf, Waf);

    // ---- layers: 2 dispatches each (BN folded into consumers) ----
    const short* src = Hhi;
    for (int i = 0; i < NLAYERS; i++) {
        const float* st = (i == 0) ? nullptr : stat + (size_t)(i - 1) * STATW * 256;
        const float* gm = (i == 0) ? nullptr : gamma + (i - 1) * 128;
        const float* bt = (i == 0) ? nullptr : beta + (i - 1) * 128;
        short* Ci = Cbf + (size_t)i * NNODES * 128;
        agg_kernel<<<(NNODES + 15) / 16, 256, 0, stream>>>(src, Ehi, local_excl,
                                                           part, epg, st, gm, bt,
                                                           Ahi);
        layer_gemm<<<(NNODES + 127) / 128, 256, 0, stream>>>(
            Ahi, src, st, gm, bt, Bf + (size_t)i * 65536, bl + i * 128, Ci,
            stat + (size_t)i * STATW * 256);
        src = Ci;
    }

    // ---- pooling: one block per (graph, layer), no atomics ----
    pool5<<<NGRAPHS * NLAYERS, 256, 0, stream>>>(
        Cbf, stat, gamma, beta, batch, out, out + (size_t)NGRAPHS * 640);
}

// Round 16
// 476.183 us; speedup vs baseline: 1.0376x; 1.0376x over previous
//
#include <hip/hip_runtime.h>
#include <hip/hip_bf16.h>

#define NNODES 50000
#define NEDGES 600000
#define NGRAPHS 128
#define EMB 128
#define NLAYERS 5
#define BN_EPS 1e-5f
#define STATW 8                               // stat fanout ways
#define SCAN_BLOCKS ((NNODES + 255) / 256)    // 196
#define NSB2 ((NNODES + 31) / 32)             // 1563 node_S blocks (8 lanes/node)
#define EAMB ((NNODES + 127) / 128)           // 391 enc_atom MFMA blocks
#define BPB2 ((NLAYERS * 32768 + 255) / 256)  // 640 bprep blocks (Wl/Wr only)

typedef short s16x8 __attribute__((ext_vector_type(8)));
typedef float f32x16 __attribute__((ext_vector_type(16)));

__device__ __forceinline__ short f2bf(float f) {
    unsigned u = __builtin_bit_cast(unsigned, f);
    unsigned r = (u + 0x7fffu + ((u >> 16) & 1u)) >> 16;  // RNE
    return (short)r;
}
__device__ __forceinline__ float bf2f(short s) {
    return __builtin_bit_cast(float, ((unsigned)(unsigned short)s) << 16);
}

// sum the STATW fanout copies for column t (t<128): returns {sum, sumsq}
__device__ __forceinline__ float2 stat_sum(const float* __restrict__ st, int t) {
    float s = 0.f, q = 0.f;
#pragma unroll
    for (int k = 0; k < STATW; k++) {
        s += st[k * 256 + t];
        q += st[k * 256 + 128 + t];
    }
    return make_float2(s, q);
}

// ---------------- init: zero deg/stat + build Wa MFMA fragments --------------
// Waf built HERE (dispatch 1) so prep2's enc_atom consumes it across a
// dispatch boundary — no intra-dispatch producer/consumer race (R13 lesson).
__global__ __launch_bounds__(256) void init_kernel(int* __restrict__ deg,
                                                   float* __restrict__ stat,
                                                   const float* __restrict__ Wa,
                                                   short* __restrict__ Waf) {
    int i = blockIdx.x * 256 + threadIdx.x;
    if (i < NNODES) deg[i] = 0;
    if (i < NLAYERS * STATW * 256) stat[i] = 0.f;
    if (i < 48 * 128) {
        int k = i >> 7, col = i & 127;
        float w = Wa[k * 128 + col];
        short hi = f2bf(w);
        short lo = f2bf(w - bf2f(hi));
        int ks = k >> 4, half = (k >> 3) & 1, j = k & 7;
        int nt = col >> 5, n32 = col & 31;
        int fo = ((nt * 2 + half) * 32 + n32) * 8 + j;
        Waf[ks * 4096 + fo] = hi;
        Waf[ks * 4096 + 2048 + fo] = lo;
    }
}

// ---------------- deg histogram + per-edge rank (atomic return value) --------
__global__ __launch_bounds__(256) void deg_kernel(const int* __restrict__ ei,
                                                  int* __restrict__ deg,
                                                  int* __restrict__ rank) {
    int e = blockIdx.x * 256 + threadIdx.x;
    if (e >= NEDGES) return;
    rank[e] = atomicAdd(&deg[ei[NEDGES + e]], 1);
}

// ---------------- scan, 2 dispatches ----------------------------------------
__global__ __launch_bounds__(256) void scan1(const int* __restrict__ deg,
                                             int* __restrict__ local_excl,
                                             int* __restrict__ part) {
    __shared__ int sh[256];
    int t = threadIdx.x;
    int i = blockIdx.x * 256 + t;
    int v = (i < NNODES) ? deg[i] : 0;
    sh[t] = v;
    __syncthreads();
    for (int off = 1; off < 256; off <<= 1) {
        int u = (t >= off) ? sh[t - off] : 0;
        __syncthreads();
        sh[t] += u;
        __syncthreads();
    }
    if (i < NNODES) local_excl[i] = sh[t] - v;
    if (t == 255) part[blockIdx.x] = sh[255];
}

// merged scan2+scan3: every block redundantly scans the 196 partials in LDS.
__global__ __launch_bounds__(256) void scan23(const int* __restrict__ part,
                                              const int* __restrict__ local_excl,
                                              int* __restrict__ rowptr) {
    __shared__ int sh[256];
    int t = threadIdx.x;
    int v = (t < SCAN_BLOCKS) ? part[t] : 0;
    sh[t] = v;
    __syncthreads();
    for (int off = 1; off < 256; off <<= 1) {
        int u = (t >= off) ? sh[t - off] : 0;
        __syncthreads();
        sh[t] += u;
        __syncthreads();
    }
    int bo = (blockIdx.x == 0) ? 0 : sh[blockIdx.x - 1];
    int i = blockIdx.x * 256 + t;
    if (i < NNODES) rowptr[i] = local_excl[i] + bo;
    if (blockIdx.x == 0 && t == 0) rowptr[NNODES] = sh[SCAN_BLOCKS - 1];
}

// ---------------- fill CSR: pos = rowptr[dst] + rank[e], NO atomic -----------
__global__ __launch_bounds__(256) void edge_fill(const int* __restrict__ ei,
                                                 const float* __restrict__ ew,
                                                 const float* __restrict__ eattr,
                                                 const int* __restrict__ rowptr,
                                                 const int* __restrict__ rank,
                                                 int* __restrict__ epk) {
    int e = blockIdx.x * 256 + threadIdx.x;
    if (e >= NEDGES) return;
    int src = ei[e];
    int dst = ei[NEDGES + e];
    int pos = rowptr[dst] + rank[e];
    int pk[8];
    pk[0] = src;
    pk[1] = __float_as_int(ew[e]);
    unsigned short a[12];
#pragma unroll
    for (int j = 0; j < 11; j++) a[j] = (unsigned short)f2bf(eattr[e * 11 + j]);
    a[11] = 0;
#pragma unroll
    for (int j = 0; j < 6; j++)
        pk[2 + j] = (int)a[2 * j] | ((int)a[2 * j + 1] << 16);
    int* dstp = epk + (size_t)pos * 8;
    *(int4*)dstp = *(int4*)pk;
    *(int4*)(dstp + 4) = *(int4*)(pk + 4);
}

// ---------------- prep2: {node_S (8 lanes/node) | enc_atom MFMA | bprep} -----
__global__ __launch_bounds__(256) void prep2(const int* __restrict__ rowptr,
                                             const int* __restrict__ epk,
                                             int2* __restrict__ epg,
                                             const float* __restrict__ Wb,
                                             const float* __restrict__ bbond,
                                             short* __restrict__ Ehi,
                                             const float* __restrict__ X,
                                             const float* __restrict__ ba,
                                             short* __restrict__ Hhi,
                                             const float* __restrict__ Wl,
                                             const float* __restrict__ Wr,
                                             short* __restrict__ Bf,
                                             const short* __restrict__ Waf) {
    __shared__ float shpool[1536];  // node_S: Wb_s 1408 + bb_s 128
    int blk = blockIdx.x;
    int t = threadIdx.x;

    if (blk < NSB2) {
        // ---- node_S: 8 lanes per node stride the edge list; shfl-reduce ----
        float* Wb_s = shpool;        // 11*128
        float* bb_s = shpool + 1408; // 128
        for (int i = t; i < 1408; i += 256) Wb_s[i] = Wb[i];
        if (t < 128) bb_s[t] = bbond[t];
        __syncthreads();
        int sub = t & 7, slot = t >> 3;
        int node = blk * 32 + slot;
        float s[11];
#pragma unroll
        for (int j = 0; j < 11; j++) s[j] = 0.f;
        float ws = 0.f;
        if (node < NNODES) {
            int b = rowptr[node], e = rowptr[node + 1];
            for (int p = b + sub; p < e; p += 8) {
                const int* pk = epk + (size_t)p * 8;
                int4 lo = *(const int4*)pk;
                int4 hi = *(const int4*)(pk + 4);
                float w = __int_as_float(lo.y);
                ws += w;
                epg[p] = make_int2(lo.x, lo.y);   // compact {src,w} record
                int packed[6] = {lo.z, lo.w, hi.x, hi.y, hi.z, hi.w};
#pragma unroll
                for (int j = 0; j < 11; j++) {
                    short v = (short)((packed[j >> 1] >> ((j & 1) * 16)) & 0xffff);
                    s[j] += bf2f(v) * w;
                }
            }
        }
        // butterfly reduce across the node's 8 lanes
#pragma unroll
        for (int m = 1; m < 8; m <<= 1) {
#pragma unroll
            for (int j = 0; j < 11; j++) s[j] += __shfl_xor(s[j], m);
            ws += __shfl_xor(ws, m);
        }
        if (node < NNODES) {
            int c0 = sub * 16;
            short* erow = Ehi + (size_t)node * 128 + c0;
#pragma unroll
            for (int cc = 0; cc < 2; cc++) {
                s16x8 o;
#pragma unroll
                for (int jj = 0; jj < 8; jj++) {
                    int c = c0 + cc * 8 + jj;
                    float a = bb_s[c] * ws;
#pragma unroll
                    for (int j = 0; j < 11; j++) a += s[j] * Wb_s[j * 128 + c];
                    o[jj] = f2bf(a);
                }
                *(s16x8*)(erow + cc * 8) = o;
            }
        }
    } else if (blk < NSB2 + EAMB) {
        // ---- enc_atom via MFMA: h0 = X @ Wa + ba, K=48 = 3 k-steps ----
        // Waf produced by init_kernel (earlier dispatch) — no race.
        int wave = t >> 6, lane = t & 63;
        int n32 = lane & 31, half = lane >> 5;
        int row0 = (blk - NSB2) * 128 + wave * 32;
        int myrow = row0 + n32;
        bool rowok = myrow < NNODES;
        f32x16 acc[4];
#pragma unroll
        for (int i = 0; i < 4; i++) acc[i] = (f32x16)(0.f);
        const short* wb0 = Waf + half * 256 + n32 * 8;
#pragma unroll
        for (int ks = 0; ks < 3; ks++) {
            s16x8 ah = {0, 0, 0, 0, 0, 0, 0, 0};
            if (rowok) {
                const float* xp = X + (size_t)myrow * 48 + ks * 16 + half * 8;
                float4 x0 = *(const float4*)xp;
                float4 x1 = *(const float4*)(xp + 4);
                ah[0] = f2bf(x0.x); ah[1] = f2bf(x0.y);
                ah[2] = f2bf(x0.z); ah[3] = f2bf(x0.w);
                ah[4] = f2bf(x1.x); ah[5] = f2bf(x1.y);
                ah[6] = f2bf(x1.z); ah[7] = f2bf(x1.w);
            }
            const short* wbn = wb0 + ks * 4096;
#pragma unroll
            for (int nt = 0; nt < 4; nt++) {
                s16x8 bh = *(const s16x8*)(wbn + nt * 512);
                s16x8 bl = *(const s16x8*)(wbn + 2048 + nt * 512);
                acc[nt] = __builtin_amdgcn_mfma_f32_32x32x16_bf16(ah, bh, acc[nt], 0, 0, 0);
                acc[nt] = __builtin_amdgcn_mfma_f32_32x32x16_bf16(ah, bl, acc[nt], 0, 0, 0);
            }
        }
#pragma unroll
        for (int nt = 0; nt < 4; nt++) {
            int col = nt * 32 + n32;
            float bb = ba[col];
#pragma unroll
            for (int reg = 0; reg < 16; reg++) {
                int r = row0 + (reg & 3) + 8 * (reg >> 2) + 4 * half;
                if (r < NNODES) Hhi[(size_t)r * 128 + col] = f2bf(acc[nt][reg] + bb);
            }
        }
    } else {
        // ---- bprep: Wl/Wr fragments, hi/lo planes ----
        int idx = (blk - NSB2 - EAMB) * 256 + t;
        if (idx >= NLAYERS * 32768) return;
        int layer = idx >> 15;
        int r = idx & 32767;
        int k = r >> 7, col = r & 127;
        float w = (k < 128) ? Wl[layer * 16384 + k * 128 + col]
                            : Wr[layer * 16384 + (k - 128) * 128 + col];
        short hi = f2bf(w);
        short lo = f2bf(w - bf2f(hi));
        int ks = k >> 4, half = (k >> 3) & 1, j = k & 7;
        int nt = col >> 5, n32 = col & 31;
        int fo = ((nt * 2 + half) * 32 + n32) * 8 + j;
        short* base = Bf + (size_t)layer * 65536 + ks * 4096;
        base[fo] = hi;
        base[2048 + fo] = lo;
    }
}

// ---------------- aggregation with inline BN+ReLU of the source -------------
__global__ __launch_bounds__(256) void agg_kernel(const short* __restrict__ Hsrc,
                                                  const short* __restrict__ Ehi,
                                                  const int* __restrict__ rowptr,
                                                  const int2* __restrict__ epg,
                                                  const float* __restrict__ stat,
                                                  const float* __restrict__ gamma,
                                                  const float* __restrict__ beta,
                                                  short* __restrict__ Ahi) {
    __shared__ float cscs[128], cshs[128];
    int t = threadIdx.x;
    if (t < 128) {
        float sc = 1.f, sh = 0.f;
        if (stat) {
            const float invM = 1.f / (float)NNODES;
            float2 sq = stat_sum(stat, t);
            float mu = sq.x * invM;
            float var = sq.y * invM - mu * mu;
            sc = gamma[t] * rsqrtf(var + BN_EPS);
            sh = beta[t] - mu * sc;
        }
        cscs[t] = sc;
        cshs[t] = sh;
    }
    __syncthreads();
    int lane = t & 15, grp = t >> 4;
    int c8 = lane * 8;
    int node = blockIdx.x * 16 + grp;
    if (node >= NNODES) return;
    float rlo = stat ? 0.f : -3.4e38f;
    float sc[8], sh[8];
#pragma unroll
    for (int j = 0; j < 8; j++) { sc[j] = cscs[c8 + j]; sh[j] = cshs[c8 + j]; }
    int b = rowptr[node], e = rowptr[node + 1];
    float s[8];
#pragma unroll
    for (int j = 0; j < 8; j++) s[j] = 0.f;
    int p = b;
    for (; p + 3 < e; p += 4) {
        int2 e0 = epg[p], e1 = epg[p + 1], e2 = epg[p + 2], e3 = epg[p + 3];
        float w0 = __int_as_float(e0.y), w1 = __int_as_float(e1.y);
        float w2 = __int_as_float(e2.y), w3 = __int_as_float(e3.y);
        s16x8 h0 = *(const s16x8*)&Hsrc[(size_t)e0.x * 128 + c8];
        s16x8 h1 = *(const s16x8*)&Hsrc[(size_t)e1.x * 128 + c8];
        s16x8 h2 = *(const s16x8*)&Hsrc[(size_t)e2.x * 128 + c8];
        s16x8 h3 = *(const s16x8*)&Hsrc[(size_t)e3.x * 128 + c8];
#pragma unroll
        for (int j = 0; j < 8; j++) {
            float v0 = fmaxf(bf2f(h0[j]) * sc[j] + sh[j], rlo);
            float v1 = fmaxf(bf2f(h1[j]) * sc[j] + sh[j], rlo);
            float v2 = fmaxf(bf2f(h2[j]) * sc[j] + sh[j], rlo);
            float v3 = fmaxf(bf2f(h3[j]) * sc[j] + sh[j], rlo);
            s[j] += v0 * w0 + v1 * w1 + v2 * w2 + v3 * w3;
        }
    }
    for (; p < e; p++) {
        int2 pk0 = epg[p];
        float w0 = __int_as_float(pk0.y);
        s16x8 h0 = *(const s16x8*)&Hsrc[(size_t)pk0.x * 128 + c8];
#pragma unroll
        for (int j = 0; j < 8; j++)
            s[j] += fmaxf(bf2f(h0[j]) * sc[j] + sh[j], rlo) * w0;
    }
    float inv = 1.f / fmaxf((float)(e - b), 1.f);
    s16x8 ea = *(const s16x8*)&Ehi[(size_t)node * 128 + c8];
    s16x8 o;
#pragma unroll
    for (int j = 0; j < 8; j++) o[j] = f2bf((s[j] + bf2f(ea[j])) * inv);
    *(s16x8*)&Ahi[(size_t)node * 128 + c8] = o;
}

// ---------------- MFMA GEMM (128-row blocks, 4 waves x 128 cols) -------------
// BN inline on h@Wr half; stat atomics fanned 8 ways (slot = blockIdx&7).
__global__ __launch_bounds__(256) void layer_gemm(const short* __restrict__ Ahi,
                                                  const short* __restrict__ Hsrc,
                                                  const float* __restrict__ statp,
                                                  const float* __restrict__ gamma,
                                                  const float* __restrict__ beta,
                                                  const short* __restrict__ Bf,
                                                  const float* __restrict__ bias,
                                                  short* __restrict__ Cbf,
                                                  float* __restrict__ stat) {
    __shared__ float s_s[128], s_q[128];
    __shared__ float csc[128], csh[128];
    int t = threadIdx.x;
    int wave = t >> 6, lane = t & 63;
    int n32 = lane & 31, half = lane >> 5;
    int row0 = blockIdx.x * 128 + wave * 32;

    if (t < 128) {
        s_s[t] = 0.f;
        s_q[t] = 0.f;
        float sc = 1.f, sh = 0.f;
        if (statp) {
            const float invM = 1.f / (float)NNODES;
            float2 sq = stat_sum(statp, t);
            float mu = sq.x * invM;
            float var = sq.y * invM - mu * mu;
            sc = gamma[t] * rsqrtf(var + BN_EPS);
            sh = beta[t] - mu * sc;
        }
        csc[t] = sc;
        csh[t] = sh;
    }
    __syncthreads();
    float rlo = statp ? 0.f : -3.4e38f;

    int myrow = row0 + n32;
    bool rowok = myrow < NNODES;
    size_t rbase = (size_t)myrow * 128;
    int acol = half * 8;

    f32x16 acc[4];
#pragma unroll
    for (int i = 0; i < 4; i++) acc[i] = (f32x16)(0.f);

    const short* bb0 = Bf + half * 256 + n32 * 8;

    s16x8 ahA = {0, 0, 0, 0, 0, 0, 0, 0}, ahB = {0, 0, 0, 0, 0, 0, 0, 0};
    s16x8 bhA[4], blA[4], bhB[4], blB[4];
    if (rowok) {
        ahA = *(const s16x8*)(Ahi + rbase + acol);
        ahB = *(const s16x8*)(Ahi + rbase + 16 + acol);
    }
#pragma unroll
    for (int nt = 0; nt < 4; nt++) {
        bhA[nt] = *(const s16x8*)(bb0 + nt * 512);
        blA[nt] = *(const s16x8*)(bb0 + 2048 + nt * 512);
        bhB[nt] = *(const s16x8*)(bb0 + 4096 + nt * 512);
        blB[nt] = *(const s16x8*)(bb0 + 4096 + 2048 + nt * 512);
    }

#pragma unroll
    for (int ks = 0; ks < 16; ks++) {
        s16x8 ahC = {0, 0, 0, 0, 0, 0, 0, 0};
        s16x8 bhC[4], blC[4];
        if (ks < 14) {
            int kn = ks + 2;
            if (rowok) {
                if (kn < 8) {
                    ahC = *(const s16x8*)(Ahi + rbase + kn * 16 + acol);
                } else {
                    s16x8 hv = *(const s16x8*)(Hsrc + rbase + (kn & 7) * 16 + acol);
                    int kc = (kn & 7) * 16 + acol;
#pragma unroll
                    for (int j = 0; j < 8; j++)
                        ahC[j] = f2bf(fmaxf(bf2f(hv[j]) * csc[kc + j] +
                                            csh[kc + j], rlo));
                }
            }
            const short* bbn = bb0 + kn * 4096;
#pragma unroll
            for (int nt = 0; nt < 4; nt++) {
                bhC[nt] = *(const s16x8*)(bbn + nt * 512);
                blC[nt] = *(const s16x8*)(bbn + 2048 + nt * 512);
            }
        }
#pragma unroll
        for (int nt = 0; nt < 4; nt++) {
            acc[nt] = __builtin_amdgcn_mfma_f32_32x32x16_bf16(ahA, bhA[nt], acc[nt], 0, 0, 0);
            acc[nt] = __builtin_amdgcn_mfma_f32_32x32x16_bf16(ahA, blA[nt], acc[nt], 0, 0, 0);
        }
        ahA = ahB;
        ahB = ahC;
#pragma unroll
        for (int nt = 0; nt < 4; nt++) {
            bhA[nt] = bhB[nt];
            blA[nt] = blB[nt];
            bhB[nt] = bhC[nt];
            blB[nt] = blC[nt];
        }
    }

    // epilogue: bias, bf16 C write, fused BN partial stats
#pragma unroll
    for (int nt = 0; nt < 4; nt++) {
        int col = nt * 32 + n32;
        float bb = bias[col];
        float ss = 0.f, qq = 0.f;
#pragma unroll
        for (int reg = 0; reg < 16; reg++) {
            int r = row0 + (reg & 3) + 8 * (reg >> 2) + 4 * half;
            if (r < NNODES) {
                float v = acc[nt][reg] + bb;
                Cbf[(size_t)r * 128 + col] = f2bf(v);
                ss += v;
                qq += v * v;
            }
        }
        ss += __shfl_xor(ss, 32);
        qq += __shfl_xor(qq, 32);
        if (half == 0) {
            atomicAdd(&s_s[col], ss);
            atomicAdd(&s_q[col], qq);
        }
    }
    __syncthreads();
    if (t < 128) {
        int slot = blockIdx.x & (STATW - 1);
        atomicAdd(&stat[slot * 256 + t], s_s[t]);
        atomicAdd(&stat[slot * 256 + 128 + t], s_q[t]);
    }
}

// ---------------- pool5: one block per (graph, layer), NO atomics ------------
__global__ __launch_bounds__(256) void pool5(const short* __restrict__ Cbf,
                                             const float* __restrict__ stat,
                                             const float* __restrict__ gamma,
                                             const float* __restrict__ beta,
                                             const int* __restrict__ batch,
                                             float* __restrict__ pool,
                                             float* __restrict__ Hf32) {
    __shared__ float csc[128], csh[128];
    __shared__ float sred[8][128];
    __shared__ int srange[2];
    int t = threadIdx.x;
    int u = blockIdx.x;
    int g = u / NLAYERS, l = u - g * NLAYERS;
    if (t < 2) {
        int target = g + t;
        int lo = 0, hi = NNODES;
        while (lo < hi) {
            int mid = (lo + hi) >> 1;
            if (batch[mid] < target) lo = mid + 1; else hi = mid;
        }
        srange[t] = lo;
    }
    if (t < 128) {
        const float invM = 1.f / (float)NNODES;
        float2 sq = stat_sum(stat + l * STATW * 256, t);
        float mu = sq.x * invM;
        float var = sq.y * invM - mu * mu;
        float sc = gamma[l * 128 + t] * rsqrtf(var + BN_EPS);
        csc[t] = sc;
        csh[t] = beta[l * 128 + t] - mu * sc;
    }
    __syncthreads();
    int gstart = srange[0], gend = srange[1];
    int lane = t & 31, grp = t >> 5;
    int c4 = lane * 4;
    float4 sc = *(const float4*)&csc[c4];
    float4 sh = *(const float4*)&csh[c4];
    const short* Cl = Cbf + (size_t)l * NNODES * 128;
    float4 accp = make_float4(0.f, 0.f, 0.f, 0.f);
    int relu = (l < NLAYERS - 1);
    for (int r = gstart + grp; r < gend; r += 8) {
        ushort4 cv = *(const ushort4*)&Cl[(size_t)r * 128 + c4];
        float4 v;
        v.x = bf2f((short)cv.x) * sc.x + sh.x;
        v.y = bf2f((short)cv.y) * sc.y + sh.y;
        v.z = bf2f((short)cv.z) * sc.z + sh.z;
        v.w = bf2f((short)cv.w) * sc.w + sh.w;
        if (relu) {
            v.x = fmaxf(v.x, 0.f);
            v.y = fmaxf(v.y, 0.f);
            v.z = fmaxf(v.z, 0.f);
            v.w = fmaxf(v.w, 0.f);
        } else {
            *(float4*)&Hf32[(size_t)r * 128 + c4] = v;
        }
        accp.x += v.x;
        accp.y += v.y;
        accp.z += v.z;
        accp.w += v.w;
    }
    sred[grp][c4 + 0] = accp.x;
    sred[grp][c4 + 1] = accp.y;
    sred[grp][c4 + 2] = accp.z;
    sred[grp][c4 + 3] = accp.w;
    __syncthreads();
    if (t < 128) {
        float s = 0.f;
#pragma unroll
        for (int k = 0; k < 8; k++) s += sred[k][t];
        pool[(size_t)g * 640 + l * 128 + t] = s;
    }
}

extern "C" void kernel_launch(void* const* d_in, const int* in_sizes, int n_in,
                              void* d_out, int out_size, void* d_ws, size_t ws_size,
                              hipStream_t stream) {
    const int* batch = (const int*)d_in[0];
    const float* x = (const float*)d_in[1];
    const int* edge_index = (const int*)d_in[2];
    const float* edge_attr = (const float*)d_in[3];
    const float* edge_weight = (const float*)d_in[4];
    const float* W_atom = (const float*)d_in[5];
    const float* b_atom = (const float*)d_in[6];
    const float* W_bond = (const float*)d_in[7];
    const float* b_bond = (const float*)d_in[8];
    const float* Wl = (const float*)d_in[9];
    const float* bl = (const float*)d_in[10];
    const float* Wr = (const float*)d_in[11];
    const float* gamma = (const float*)d_in[12];
    const float* beta = (const float*)d_in[13];
    float* out = (float*)d_out;

    // ---- workspace layout ----
    char* ws = (char*)d_ws;
    size_t off = 0;
    auto alloc = [&](size_t bytes) -> void* {
        void* p = ws + off;
        off += (bytes + 255) & ~(size_t)255;
        return p;
    };
    short* Hhi = (short*)alloc((size_t)NNODES * 128 * 2);
    short* Ahi = (short*)alloc((size_t)NNODES * 128 * 2);
    short* Ehi = (short*)alloc((size_t)NNODES * 128 * 2);
    short* Cbf = (short*)alloc((size_t)NLAYERS * NNODES * 128 * 2);  // 5 layers
    int* epk = (int*)alloc((size_t)NEDGES * 32);
    int2* epg = (int2*)alloc((size_t)NEDGES * 8);
    int* rank = (int*)alloc((size_t)NEDGES * 4);
    int* rowptr = (int*)alloc((size_t)(NNODES + 1) * 4);
    int* deg = (int*)alloc((size_t)NNODES * 4);
    float* stat = (float*)alloc(NLAYERS * STATW * 256 * 4);
    int* local_excl = (int*)alloc((size_t)NNODES * 4);
    int* part = (int*)alloc(SCAN_BLOCKS * 4);
    short* Bf = (short*)alloc((size_t)NLAYERS * 65536 * 2);
    short* Waf = (short*)alloc((size_t)3 * 4096 * 2);

    // ---- preprocessing (6 dispatches) ----
    init_kernel<<<SCAN_BLOCKS, 256, 0, stream>>>(deg, stat, W_atom, Waf);
    deg_kernel<<<(NEDGES + 255) / 256, 256, 0, stream>>>(edge_index, deg, rank);
    scan1<<<SCAN_BLOCKS, 256, 0, stream>>>(deg, local_excl, part);
    scan23<<<SCAN_BLOCKS, 256, 0, stream>>>(part, local_excl, rowptr);
    edge_fill<<<(NEDGES + 255) / 256, 256, 0, stream>>>(edge_index, edge_weight,
                                                        edge_attr, rowptr, rank, epk);
    prep2<<<NSB2 + EAMB + BPB2, 256, 0, stream>>>(rowptr, epk, epg, W_bond, b_bond,
                                                  Ehi, x, b_atom, Hhi,
                                                  Wl, Wr, Bf, Waf);

    // ---- layers: 2 dispatches each (BN folded into consumers) ----
    const short* src = Hhi;
    for (int i = 0; i < NLAYERS; i++) {
        const float* st = (i == 0) ? nullptr : stat + (size_t)(i - 1) * STATW * 256;
        const float* gm = (i == 0) ? nullptr : gamma + (i - 1) * 128;
        const float* bt = (i == 0) ? nullptr : beta + (i - 1) * 128;
        short* Ci = Cbf + (size_t)i * NNODES * 128;
        agg_kernel<<<(NNODES + 15) / 16, 256, 0, stream>>>(src, Ehi, rowptr, epg,
                                                           st, gm, bt, Ahi);
        layer_gemm<<<(NNODES + 127) / 128, 256, 0, stream>>>(
            Ahi, src, st, gm, bt, Bf + (size_t)i * 65536, bl + i * 128, Ci,
            stat + (size_t)i * STATW * 256);
        src = Ci;
    }

    // ---- pooling: one block per (graph, layer), no atomics ----
    pool5<<<NGRAPHS * NLAYERS, 256, 0, stream>>>(
        Cbf, stat, gamma, beta, batch, out, out + (size_t)NGRAPHS * 640);
}